// Round 14
// baseline (341.771 us; speedup 1.0000x reference)
//
#include <hip/hip_runtime.h>
#include <hip/hip_bf16.h>

// ============================================================================
// Head: K=x@Wk^T, Q=x@Wq^T, V=x@Wv^T, causal softmax(QK^T/8)@V
// B=4, T=4096, D=1024, H=64. fp32 I/O, bf16 MFMA compute.
//
// R19 = R17 resubmit (rounds 12/13 died to broker capacity, never measured).
// R17 = R16 (verified 340.7us; attn 186us, Mfma 21.2 / VALU 35.4 / Occ 36.3)
// with ONE change: swapped QK MFMA (S^T fragment) -> b64 P-writes.
//  Why: VALU is the top busy pipe; computeP's P-writeback was 4 scalar
//  ds_write_b16 + scatter addressing per strip (output frag had q on rows).
//  mfma(K,Q) instead of mfma(Q,K): A/B frags have identical lane layouts so
//  NO load changes; output lane holds P[q=l15][s=quad*4+r] = 4 consecutive
//  s in one Plds row -> one aligned ds_write_b64 per strip (2 stores/iter
//  vs 8). Mask re-indexed (same coverage). PV/accl/schedule identical.
//
// FENCED (R6=NaN / R11=3.6e5): {v_cvt_pk_bf16_f32 asm, __builtin_amdgcn_exp2f,
// s_setprio} in attn_fa — register/LDS corruption at the 128-reg wall.
// Dead: V-in-registers (R10 spills); 64-row 4-wave blocks (R9 drain-out);
// more waves (R13/R14: +50% occupancy, 0% speedup).
// ============================================================================

typedef __attribute__((ext_vector_type(8))) short bf16x8;   // 8 bf16, 4 VGPRs
typedef __attribute__((ext_vector_type(4))) float f32x4;

typedef unsigned short u16;
typedef unsigned int u32;

__device__ inline u16 f2bf(float f) {
    u32 u = __builtin_bit_cast(u32, f);
    u = (u + 0x7fff + ((u >> 16) & 1)) >> 16;   // RNE
    return (u16)u;
}

__device__ inline u32 pkbf(float a, float b) {  // bf16(a) | bf16(b)<<16
    return (u32)f2bf(a) | ((u32)f2bf(b) << 16);
}

__device__ inline void g2lds16(const void* g, void* l) {
    __builtin_amdgcn_global_load_lds(
        (const __attribute__((address_space(1))) unsigned int*)g,
        (__attribute__((address_space(3))) unsigned int*)l, 16, 0, 0);
}

// Fragment-tile addressing (16 rows x 32 k, 512 u16 = 1KB per tile):
//   element (r, k): u16 idx = ((r&15) + ((k>>3)&3)*16)*8 + (k&7)
// A-frag (m=lane&15, k=quad*8+j) and B-frag (n=lane&15, k=quad*8+j) reads are
// both "base + lane*16B" -> coalesced global / conflict-free LDS.

// ----------------------------------------------------------------------------
__global__ void cvt_x(const float* __restrict__ src, u16* __restrict__ dst,
                      int n) {
    const int i = (blockIdx.x * blockDim.x + threadIdx.x) * 8;
    if (i + 7 < n) {
        const float4 a = *(const float4*)(src + i);
        const float4 b = *(const float4*)(src + i + 4);
        u32 r[4];
        r[0] = pkbf(a.x, a.y);
        r[1] = pkbf(a.z, a.w);
        r[2] = pkbf(b.x, b.y);
        r[3] = pkbf(b.z, b.w);
        *(uint4*)(dst + i) = *(const uint4*)r;
    }
}

// Fused weight convert: Wk (1x), Wq (x 0.125*log2e), Wv (1x).
__global__ void cvt_w(const float* __restrict__ Wk, const float* __restrict__ Wq,
                      const float* __restrict__ Wv,
                      u16* __restrict__ Wkb, u16* __restrict__ Wqb,
                      u16* __restrict__ Wvb, float qscale) {
    const int i = (blockIdx.x * blockDim.x + threadIdx.x) * 8;
    const float* src; u16* dst; int j; float s = 1.0f;
    if (i < 65536)        { src = Wk; dst = Wkb; j = i; }
    else if (i < 131072)  { src = Wq; dst = Wqb; j = i - 65536; s = qscale; }
    else                  { src = Wv; dst = Wvb; j = i - 131072; }
    const float4 a = *(const float4*)(src + j);
    const float4 b = *(const float4*)(src + j + 4);
    u32 r[4];
    r[0] = pkbf(a.x * s, a.y * s);
    r[1] = pkbf(a.z * s, a.w * s);
    r[2] = pkbf(b.x * s, b.y * s);
    r[3] = pkbf(b.z * s, b.w * s);
    *(uint4*)(dst + j) = *(const uint4*)r;
}

// ----------------------------------------------------------------------------
// GEMM body: C = A[M][K] @ Bsel[N][K]^T, bf16, fp32 accum, 128x128, BK=64.
// lda = ldb = K = 1024. Outputs frag-tiled (MODE 1: Qf/Kf, MODE 2: Vf).
// ----------------------------------------------------------------------------
template <int MODE>
__device__ __forceinline__ void gemm_body(
    int m0, int n0,
    const u16* __restrict__ A,
    const u16* __restrict__ B0, const u16* __restrict__ B1, int nsplit,
    u16* __restrict__ D0, u16* __restrict__ D1,
    u16* Alds, u16* Blds)
{
    const int tid  = threadIdx.x;
    const int lane = tid & 63, w = tid >> 6;
    const int quad = lane >> 4, l15 = lane & 15;
    const int wr = w >> 1, wc = w & 1;
    const int mrow0 = wr * 64, ncol0 = wc * 64;

    f32x4 acc[4][4] = {};

    const int srow = (lane >> 3);
    const int scol = (lane & 7) * 8;

    for (int k0 = 0; k0 < 1024; k0 += 64) {
        __syncthreads();
#pragma unroll
        for (int c = 0; c < 4; ++c) {
            const int chunk = c * 4 + w;
            const int row = chunk * 8 + srow;
            const u16* ga = A + (size_t)(m0 + row) * 1024 + k0 + scol;
            g2lds16(ga, &Alds[chunk * 512]);
            const int brow = n0 + row;
            const u16* gb = (brow < nsplit ? B0 + (size_t)brow * 1024
                                           : B1 + (size_t)(brow - nsplit) * 1024)
                            + k0 + scol;
            g2lds16(gb, &Blds[chunk * 512]);
        }
        __syncthreads();

#pragma unroll
        for (int kk = 0; kk < 64; kk += 32) {
            bf16x8 af[4], bfr[4];
#pragma unroll
            for (int mb = 0; mb < 4; ++mb)
                af[mb] = *(const bf16x8*)&Alds[(mrow0 + mb * 16 + l15) * 64 + kk + quad * 8];
#pragma unroll
            for (int nb = 0; nb < 4; ++nb)
                bfr[nb] = *(const bf16x8*)&Blds[(ncol0 + nb * 16 + l15) * 64 + kk + quad * 8];
#pragma unroll
            for (int mb = 0; mb < 4; ++mb)
#pragma unroll
                for (int nb = 0; nb < 4; ++nb)
                    acc[mb][nb] = __builtin_amdgcn_mfma_f32_16x16x32_bf16(
                        af[mb], bfr[nb], acc[mb][nb], 0, 0, 0);
        }
    }

    // epilogue: C/D layout col=lane&15, row=quad*4+reg
#pragma unroll
    for (int mb = 0; mb < 4; ++mb)
#pragma unroll
        for (int nb = 0; nb < 4; ++nb)
#pragma unroll
            for (int r = 0; r < 4; ++r) {
                const int row = m0 + mrow0 + mb * 16 + quad * 4 + r;
                const int col = n0 + ncol0 + nb * 16 + l15;
                const u16 v = f2bf(acc[mb][nb][r]);
                if (MODE == 1) {
                    const int h = col & 63;
                    u16* dst = (col < 64) ? D0 : D1;
                    const size_t idx = (size_t)((row >> 4) * 2 + (h >> 5)) * 512
                                     + ((row & 15) + ((h >> 3) & 3) * 16) * 8
                                     + (h & 7);
                    dst[idx] = v;
                } else {
                    const size_t idx = (size_t)((row >> 4) * 512 + (col >> 5)) * 512
                                     + ((row & 15) + ((col >> 3) & 3) * 16) * 8
                                     + (col & 7);
                    D0[idx] = v;
                }
            }
}

// Combined GEMM dispatch: blocks [0,128) -> QK projection, [128,1152) -> Vt.
__global__ __launch_bounds__(256, 2) void gemm_all(
    const u16* __restrict__ xb,
    const u16* __restrict__ Wqb, const u16* __restrict__ Wkb,
    const u16* __restrict__ Wvb,
    u16* __restrict__ Qf, u16* __restrict__ Kf, u16* __restrict__ Vf)
{
    __shared__ u16 Alds[128 * 64];
    __shared__ u16 Blds[128 * 64];
    const int d = blockIdx.x;
    if (d < 128) {
        gemm_body<1>(d * 128, 0, xb, Wqb, Wkb, 64, Qf, Kf, Alds, Blds);
    } else {
        const int dd = d - 128;
        gemm_body<2>((dd >> 7) * 128, (dd & 127) * 128, Wvb, xb, xb, 1 << 30,
                     Vf, nullptr, Alds, Blds);
    }
}

// ----------------------------------------------------------------------------
// Flash attention, no-max softmax, es-split P handoff, software-pipelined.
// grid (128,4) flat d: g=d>>4, qt = g<16 ? 31-g : g-16 (complementary pairs),
// e0 = ((d>>2)&3)*256, b = d&3. Block 1024 thr (16 waves): wave w ->
// qs=w>>1 (16 q rows), es=w&1 (32 of the 64 s-cols in computeP; 128 e cols
// in PV). s-tile = 64: ntiles = 2qt+2. Iter order: barrier -> stageV(it+1)
// -> loadK(it+1) -> PV(it) -> computeP(it+1).
// computeP uses SWAPPED mfma(K,Q): lane holds P[q=l15][s=quad*4+r], so the
// 4 values are consecutive in a Plds row -> one ds_write_b64 per strip.
// ----------------------------------------------------------------------------
__global__ __launch_bounds__(1024, 4) void attn_fa(
    const u16* __restrict__ Qf,
    const u16* __restrict__ Kf,
    const u16* __restrict__ Vf,
    float* __restrict__ Out)
{
    __shared__ u16 Vlds[2][32 * 512];   // 2 x 32KB (e=256, s=64)
    __shared__ u16 Plds[2][128 * 72];   // 2 x 18KB block-shared P, row-pad 72

    const int tid  = threadIdx.x;
    const int lane = tid & 63, w = tid >> 6;      // w in [0,16)
    const int quad = lane >> 4, l15 = lane & 15;

    const int d  = blockIdx.y * 128 + blockIdx.x;
    const int g  = d >> 4;
    const int qt = (g < 16) ? (31 - g) : (g - 16);
    const int e0 = ((d >> 2) & 3) * 256;
    const int b  = d & 3;
    const int bt0 = b * 4096;

    const int qs = w >> 1, es = w & 1;            // qs in [0,8): 16 rows each
    const int qrow0 = qt * 128 + qs * 16;

    // Q A-frags (persistent, log2-domain scaled): one 16-row tile, K=64
    bf16x8 qf[2];
    {
        const int btile = (bt0 + qrow0) >> 4;
#pragma unroll
        for (int kk = 0; kk < 2; ++kk)
            qf[kk] = *(const bf16x8*)&Qf[(size_t)(btile * 2 + kk) * 512 + lane * 8];
    }

    // ones B-fragment for row-sum accumulation (bf16 1.0 = 0x3F80)
    const short o = (short)0x3F80;
    const bf16x8 ones = {o, o, o, o, o, o, o, o};

    f32x4 acc[8] = {};      // O accumulator [nb_e]
    f32x4 accl = {};        // row-sum accumulator

    const int ntiles = 2 * qt + 2;      // s-tiles of 64
    const int qlim = qrow0 + 15;        // wave active for tile it iff it*64 <= qlim

    // ---- stage V tile `it` (64 s-cols) into Vlds[buf]: 2KB per wave ----
    auto stageV = [&](int buf, int it) {
        const int ct0 = (bt0 >> 5) + it * 2;
#pragma unroll
        for (int h = 0; h < 2; ++h)
            g2lds16(&Vf[(size_t)(((e0 >> 4) + w) * 512 + ct0 + h) * 512 + lane * 8],
                    &Vlds[buf][(h * 16 + w) * 512]);
    };

    // ---- load this wave's K quarter for tile `jt` (4 x b128 global) ----
    auto loadK = [&](int jt, bf16x8* kf) {
#pragma unroll
        for (int cc = 0; cc < 2; ++cc)
#pragma unroll
            for (int kk = 0; kk < 2; ++kk) {
                const int kt = ((bt0 + jt * 64 + es * 32 + cc * 16) >> 4) * 2 + kk;
                kf[cc * 2 + kk] = *(const bf16x8*)&Kf[(size_t)kt * 512 + lane * 8];
            }
    };

    // ---- compute this wave's (16q x 32s) strip of P(jt) into Plds[jt&1] ----
    // SWAPPED mfma(K,Q): D[m=s][n=q] -> lane (quad,l15) holds
    // P[q=qrow0+l15][s=c0+quad*4+r], 4 consecutive s in one Plds row.
    auto computeP = [&](int jt, const bf16x8* kf) {
        const int s0 = jt * 64;
#pragma unroll
        for (int cc = 0; cc < 2; ++cc) {
            f32x4 sf = {};
#pragma unroll
            for (int kk = 0; kk < 2; ++kk)
                sf = __builtin_amdgcn_mfma_f32_16x16x32_bf16(
                    kf[cc * 2 + kk], qf[kk], sf, 0, 0, 0);
            const int c0 = s0 + es * 32 + cc * 16;
            if (c0 + 15 > qrow0) {      // diagonal-crossing: mask (s <= q)
                const int rowabs = qrow0 + l15;          // q
                const int colbase = c0 + quad * 4;       // s of reg 0
#pragma unroll
                for (int r = 0; r < 4; ++r)
                    sf[r] = (colbase + r <= rowabs) ? sf[r] : -__builtin_inff();
            }
            u32 pk[2];
            pk[0] = pkbf(exp2f(sf[0]), exp2f(sf[1]));
            pk[1] = pkbf(exp2f(sf[2]), exp2f(sf[3]));
            *(uint2*)&Plds[jt & 1][(qs * 16 + l15) * 72 + es * 32 + cc * 16 + quad * 4]
                = *(const uint2*)pk;
        }
    };

    // ---- prologue: tile 0 ----
    stageV(0, 0);
    {
        bf16x8 kf0[4];
        loadK(0, kf0);
        computeP(0, kf0);
    }

    for (int it = 0; it < ntiles; ++it) {
        __syncthreads();                 // V(it), P(it) ready (vmcnt drained)
        const int buf = it & 1;
        const bool haveNext = (it + 1 < ntiles);
        const bool nextActive = haveNext && ((it + 1) * 64 <= qlim);
        const bool curActive = (it * 64 <= qlim);

        if (haveNext) stageV(buf ^ 1, it + 1);
        bf16x8 kf[4];
        if (nextActive) loadK(it + 1, kf);

        if (curActive) {
            // ---- O += P @ V ; l += P @ 1 ---- (two s-halves h)
#pragma unroll
            for (int h = 0; h < 2; ++h) {
                const bf16x8 pf = *(const bf16x8*)
                    &Plds[buf][(qs * 16 + l15) * 72 + h * 32 + quad * 8];
                accl = __builtin_amdgcn_mfma_f32_16x16x32_bf16(pf, ones, accl, 0, 0, 0);
#pragma unroll
                for (int nb = 0; nb < 8; ++nb) {
                    bf16x8 vf = *(const bf16x8*)
                        &Vlds[buf][(h * 16 + es * 8 + nb) * 512 + lane * 8];
                    acc[nb] = __builtin_amdgcn_mfma_f32_16x16x32_bf16(
                        pf, vf, acc[nb], 0, 0, 0);
                }
            }
        }

        if (nextActive) computeP(it + 1, kf);
    }

    // ---- epilogue: normalize by row sums ----
    float rl[4];
#pragma unroll
    for (int r = 0; r < 4; ++r) rl[r] = 1.0f / accl[r];
#pragma unroll
    for (int nb = 0; nb < 8; ++nb)
#pragma unroll
        for (int r = 0; r < 4; ++r) {
            const int row = qrow0 + quad * 4 + r;
            const int col = e0 + es * 128 + nb * 16 + l15;
            Out[(size_t)(bt0 + row) * 1024 + col] = acc[nb][r] * rl[r];
        }
}

// ----------------------------------------------------------------------------
extern "C" void kernel_launch(void* const* d_in, const int* in_sizes, int n_in,
                              void* d_out, int out_size, void* d_ws, size_t ws_size,
                              hipStream_t stream) {
    const float* x  = (const float*)d_in[0];   // [4,4096,1024]
    const float* Wk = (const float*)d_in[1];   // [64,1024]
    const float* Wq = (const float*)d_in[2];   // [64,1024]
    const float* Wv = (const float*)d_in[3];   // [1024,1024]

    const int nx  = in_sizes[0];
    const int nwk = in_sizes[1];
    const int nwq = in_sizes[2];
    const int nwv = in_sizes[3];

    u16* xb  = (u16*)d_ws;
    u16* Wkb = xb  + (size_t)nx;
    u16* Wqb = Wkb + (size_t)nwk;
    u16* Wvb = Wqb + (size_t)nwq;
    u16* Qf  = Wvb + (size_t)nwv;                    // 1024 btiles * 2 * 512
    u16* Kf  = Qf  + (size_t)1024 * 2 * 512;
    u16* Vf  = Kf  + (size_t)1024 * 2 * 512;         // 64 etiles * 512 * 512
    float* out = (float*)d_out;

    const float qscale = 0.125f * 1.44269504088896f; // fold 1/sqrt(H)*log2(e)

    cvt_x<<<nx / 2048, 256, 0, stream>>>(x, xb, nx);
    cvt_w<<<(nwk + nwq + nwv) / 2048, 256, 0, stream>>>(Wk, Wq, Wv,
                                                        Wkb, Wqb, Wvb, qscale);

    gemm_all<<<1152, 256, 0, stream>>>(xb, Wqb, Wkb, Wvb, Qf, Kf, Vf);

    attn_fa<<<dim3(128, 4), 1024, 0, stream>>>(Qf, Kf, Vf, out);
}

// Round 15
// 339.438 us; speedup vs baseline: 1.0069x; 1.0069x over previous
//
#include <hip/hip_runtime.h>
#include <hip/hip_bf16.h>

// ============================================================================
// Head: K=x@Wk^T, Q=x@Wq^T, V=x@Wv^T, causal softmax(QK^T/8)@V
// B=4, T=4096, D=1024, H=64. fp32 I/O, bf16 MFMA compute.
//
// R20 = R19 (verified 341.8us; attn 187.4, tied w/ R16's 340.7) + ONE change:
// XCD-locality remap of the MODE2 (V-GEMM) block->tile mapping.
//  Why: total - attn = 154-155us across ALL verified runs; cvt ~20us =>
//  gemm_all ~130us ~ 260 TF (3x below its structural class). MODE2 streams
//  xb as B 8x (512 MB of L3 traffic, ~3.9 TB/s => ~130us). Old mapping
//  (m=dd>>7, n=dd&127): B-panel sharers are 128 blocks apart AND on
//  different XCDs -> zero L2 reuse. New mapping (g=dd&7, j=dd>>3,
//  m=j&7, n=g*16+(j>>3)): the 8 sharers have the same dd%8 -> SAME XCD
//  (blocks dispatch round-robin d%8 -> XCD), consecutive arrival ->
//  co-resident; B-panel (256KB) L2-cached once, reused 8x; cycling A
//  (Wv, 2MB) also L2-fits. B L3 traffic 512 -> ~66 MB. Bijective remap,
//  zero correctness risk. attn_fa/cvt/MODE1 byte-identical to R19.
//
// FENCED (R6=NaN / R11=3.6e5): {v_cvt_pk_bf16_f32 asm, __builtin_amdgcn_exp2f,
// s_setprio} in attn_fa — register/LDS corruption at the 128-reg wall.
// Dead: V-in-registers (R10 spills); 64-row 4-wave blocks (R9 drain-out);
// more waves (R13/R14: +50% occupancy, 0% speedup); attn micro-opts
// converged (R13 0%, R15 +7%, R17 0%).
// ============================================================================

typedef __attribute__((ext_vector_type(8))) short bf16x8;   // 8 bf16, 4 VGPRs
typedef __attribute__((ext_vector_type(4))) float f32x4;

typedef unsigned short u16;
typedef unsigned int u32;

__device__ inline u16 f2bf(float f) {
    u32 u = __builtin_bit_cast(u32, f);
    u = (u + 0x7fff + ((u >> 16) & 1)) >> 16;   // RNE
    return (u16)u;
}

__device__ inline u32 pkbf(float a, float b) {  // bf16(a) | bf16(b)<<16
    return (u32)f2bf(a) | ((u32)f2bf(b) << 16);
}

__device__ inline void g2lds16(const void* g, void* l) {
    __builtin_amdgcn_global_load_lds(
        (const __attribute__((address_space(1))) unsigned int*)g,
        (__attribute__((address_space(3))) unsigned int*)l, 16, 0, 0);
}

// Fragment-tile addressing (16 rows x 32 k, 512 u16 = 1KB per tile):
//   element (r, k): u16 idx = ((r&15) + ((k>>3)&3)*16)*8 + (k&7)
// A-frag (m=lane&15, k=quad*8+j) and B-frag (n=lane&15, k=quad*8+j) reads are
// both "base + lane*16B" -> coalesced global / conflict-free LDS.

// ----------------------------------------------------------------------------
__global__ void cvt_x(const float* __restrict__ src, u16* __restrict__ dst,
                      int n) {
    const int i = (blockIdx.x * blockDim.x + threadIdx.x) * 8;
    if (i + 7 < n) {
        const float4 a = *(const float4*)(src + i);
        const float4 b = *(const float4*)(src + i + 4);
        u32 r[4];
        r[0] = pkbf(a.x, a.y);
        r[1] = pkbf(a.z, a.w);
        r[2] = pkbf(b.x, b.y);
        r[3] = pkbf(b.z, b.w);
        *(uint4*)(dst + i) = *(const uint4*)r;
    }
}

// Fused weight convert: Wk (1x), Wq (x 0.125*log2e), Wv (1x).
__global__ void cvt_w(const float* __restrict__ Wk, const float* __restrict__ Wq,
                      const float* __restrict__ Wv,
                      u16* __restrict__ Wkb, u16* __restrict__ Wqb,
                      u16* __restrict__ Wvb, float qscale) {
    const int i = (blockIdx.x * blockDim.x + threadIdx.x) * 8;
    const float* src; u16* dst; int j; float s = 1.0f;
    if (i < 65536)        { src = Wk; dst = Wkb; j = i; }
    else if (i < 131072)  { src = Wq; dst = Wqb; j = i - 65536; s = qscale; }
    else                  { src = Wv; dst = Wvb; j = i - 131072; }
    const float4 a = *(const float4*)(src + j);
    const float4 b = *(const float4*)(src + j + 4);
    u32 r[4];
    r[0] = pkbf(a.x * s, a.y * s);
    r[1] = pkbf(a.z * s, a.w * s);
    r[2] = pkbf(b.x * s, b.y * s);
    r[3] = pkbf(b.z * s, b.w * s);
    *(uint4*)(dst + j) = *(const uint4*)r;
}

// ----------------------------------------------------------------------------
// GEMM body: C = A[M][K] @ Bsel[N][K]^T, bf16, fp32 accum, 128x128, BK=64.
// lda = ldb = K = 1024. Outputs frag-tiled (MODE 1: Qf/Kf, MODE 2: Vf).
// ----------------------------------------------------------------------------
template <int MODE>
__device__ __forceinline__ void gemm_body(
    int m0, int n0,
    const u16* __restrict__ A,
    const u16* __restrict__ B0, const u16* __restrict__ B1, int nsplit,
    u16* __restrict__ D0, u16* __restrict__ D1,
    u16* Alds, u16* Blds)
{
    const int tid  = threadIdx.x;
    const int lane = tid & 63, w = tid >> 6;
    const int quad = lane >> 4, l15 = lane & 15;
    const int wr = w >> 1, wc = w & 1;
    const int mrow0 = wr * 64, ncol0 = wc * 64;

    f32x4 acc[4][4] = {};

    const int srow = (lane >> 3);
    const int scol = (lane & 7) * 8;

    for (int k0 = 0; k0 < 1024; k0 += 64) {
        __syncthreads();
#pragma unroll
        for (int c = 0; c < 4; ++c) {
            const int chunk = c * 4 + w;
            const int row = chunk * 8 + srow;
            const u16* ga = A + (size_t)(m0 + row) * 1024 + k0 + scol;
            g2lds16(ga, &Alds[chunk * 512]);
            const int brow = n0 + row;
            const u16* gb = (brow < nsplit ? B0 + (size_t)brow * 1024
                                           : B1 + (size_t)(brow - nsplit) * 1024)
                            + k0 + scol;
            g2lds16(gb, &Blds[chunk * 512]);
        }
        __syncthreads();

#pragma unroll
        for (int kk = 0; kk < 64; kk += 32) {
            bf16x8 af[4], bfr[4];
#pragma unroll
            for (int mb = 0; mb < 4; ++mb)
                af[mb] = *(const bf16x8*)&Alds[(mrow0 + mb * 16 + l15) * 64 + kk + quad * 8];
#pragma unroll
            for (int nb = 0; nb < 4; ++nb)
                bfr[nb] = *(const bf16x8*)&Blds[(ncol0 + nb * 16 + l15) * 64 + kk + quad * 8];
#pragma unroll
            for (int mb = 0; mb < 4; ++mb)
#pragma unroll
                for (int nb = 0; nb < 4; ++nb)
                    acc[mb][nb] = __builtin_amdgcn_mfma_f32_16x16x32_bf16(
                        af[mb], bfr[nb], acc[mb][nb], 0, 0, 0);
        }
    }

    // epilogue: C/D layout col=lane&15, row=quad*4+reg
#pragma unroll
    for (int mb = 0; mb < 4; ++mb)
#pragma unroll
        for (int nb = 0; nb < 4; ++nb)
#pragma unroll
            for (int r = 0; r < 4; ++r) {
                const int row = m0 + mrow0 + mb * 16 + quad * 4 + r;
                const int col = n0 + ncol0 + nb * 16 + l15;
                const u16 v = f2bf(acc[mb][nb][r]);
                if (MODE == 1) {
                    const int h = col & 63;
                    u16* dst = (col < 64) ? D0 : D1;
                    const size_t idx = (size_t)((row >> 4) * 2 + (h >> 5)) * 512
                                     + ((row & 15) + ((h >> 3) & 3) * 16) * 8
                                     + (h & 7);
                    dst[idx] = v;
                } else {
                    const size_t idx = (size_t)((row >> 4) * 512 + (col >> 5)) * 512
                                     + ((row & 15) + ((col >> 3) & 3) * 16) * 8
                                     + (col & 7);
                    D0[idx] = v;
                }
            }
}

// Combined GEMM dispatch: blocks [0,128) -> QK projection, [128,1152) -> Vt.
// MODE2 block->tile remap for XCD/L2 locality: g=dd&7, j=dd>>3,
// m0=(j&7)*128, n0=(g*16+(j>>3))*128. The 8 blocks sharing a B-panel (same
// n0, all m0) have identical dd%8 -> same XCD, consecutive arrival -> the
// 256KB B-panel is L2-reused 8x instead of re-streamed from L3.
__global__ __launch_bounds__(256, 2) void gemm_all(
    const u16* __restrict__ xb,
    const u16* __restrict__ Wqb, const u16* __restrict__ Wkb,
    const u16* __restrict__ Wvb,
    u16* __restrict__ Qf, u16* __restrict__ Kf, u16* __restrict__ Vf)
{
    __shared__ u16 Alds[128 * 64];
    __shared__ u16 Blds[128 * 64];
    const int d = blockIdx.x;
    if (d < 128) {
        gemm_body<1>(d * 128, 0, xb, Wqb, Wkb, 64, Qf, Kf, Alds, Blds);
    } else {
        const int dd = d - 128;
        const int g = dd & 7, j = dd >> 3;
        gemm_body<2>((j & 7) * 128, (g * 16 + (j >> 3)) * 128, Wvb, xb, xb,
                     1 << 30, Vf, nullptr, Alds, Blds);
    }
}

// ----------------------------------------------------------------------------
// Flash attention, no-max softmax, es-split P handoff, software-pipelined.
// grid (128,4) flat d: g=d>>4, qt = g<16 ? 31-g : g-16 (complementary pairs),
// e0 = ((d>>2)&3)*256, b = d&3. Block 1024 thr (16 waves): wave w ->
// qs=w>>1 (16 q rows), es=w&1 (32 of the 64 s-cols in computeP; 128 e cols
// in PV). s-tile = 64: ntiles = 2qt+2. Iter order: barrier -> stageV(it+1)
// -> loadK(it+1) -> PV(it) -> computeP(it+1).
// computeP uses SWAPPED mfma(K,Q): lane holds P[q=l15][s=quad*4+r], so the
// 4 values are consecutive in a Plds row -> one ds_write_b64 per strip.
// ----------------------------------------------------------------------------
__global__ __launch_bounds__(1024, 4) void attn_fa(
    const u16* __restrict__ Qf,
    const u16* __restrict__ Kf,
    const u16* __restrict__ Vf,
    float* __restrict__ Out)
{
    __shared__ u16 Vlds[2][32 * 512];   // 2 x 32KB (e=256, s=64)
    __shared__ u16 Plds[2][128 * 72];   // 2 x 18KB block-shared P, row-pad 72

    const int tid  = threadIdx.x;
    const int lane = tid & 63, w = tid >> 6;      // w in [0,16)
    const int quad = lane >> 4, l15 = lane & 15;

    const int d  = blockIdx.y * 128 + blockIdx.x;
    const int g  = d >> 4;
    const int qt = (g < 16) ? (31 - g) : (g - 16);
    const int e0 = ((d >> 2) & 3) * 256;
    const int b  = d & 3;
    const int bt0 = b * 4096;

    const int qs = w >> 1, es = w & 1;            // qs in [0,8): 16 rows each
    const int qrow0 = qt * 128 + qs * 16;

    // Q A-frags (persistent, log2-domain scaled): one 16-row tile, K=64
    bf16x8 qf[2];
    {
        const int btile = (bt0 + qrow0) >> 4;
#pragma unroll
        for (int kk = 0; kk < 2; ++kk)
            qf[kk] = *(const bf16x8*)&Qf[(size_t)(btile * 2 + kk) * 512 + lane * 8];
    }

    // ones B-fragment for row-sum accumulation (bf16 1.0 = 0x3F80)
    const short o = (short)0x3F80;
    const bf16x8 ones = {o, o, o, o, o, o, o, o};

    f32x4 acc[8] = {};      // O accumulator [nb_e]
    f32x4 accl = {};        // row-sum accumulator

    const int ntiles = 2 * qt + 2;      // s-tiles of 64
    const int qlim = qrow0 + 15;        // wave active for tile it iff it*64 <= qlim

    // ---- stage V tile `it` (64 s-cols) into Vlds[buf]: 2KB per wave ----
    auto stageV = [&](int buf, int it) {
        const int ct0 = (bt0 >> 5) + it * 2;
#pragma unroll
        for (int h = 0; h < 2; ++h)
            g2lds16(&Vf[(size_t)(((e0 >> 4) + w) * 512 + ct0 + h) * 512 + lane * 8],
                    &Vlds[buf][(h * 16 + w) * 512]);
    };

    // ---- load this wave's K quarter for tile `jt` (4 x b128 global) ----
    auto loadK = [&](int jt, bf16x8* kf) {
#pragma unroll
        for (int cc = 0; cc < 2; ++cc)
#pragma unroll
            for (int kk = 0; kk < 2; ++kk) {
                const int kt = ((bt0 + jt * 64 + es * 32 + cc * 16) >> 4) * 2 + kk;
                kf[cc * 2 + kk] = *(const bf16x8*)&Kf[(size_t)kt * 512 + lane * 8];
            }
    };

    // ---- compute this wave's (16q x 32s) strip of P(jt) into Plds[jt&1] ----
    // SWAPPED mfma(K,Q): D[m=s][n=q] -> lane (quad,l15) holds
    // P[q=qrow0+l15][s=c0+quad*4+r], 4 consecutive s in one Plds row.
    auto computeP = [&](int jt, const bf16x8* kf) {
        const int s0 = jt * 64;
#pragma unroll
        for (int cc = 0; cc < 2; ++cc) {
            f32x4 sf = {};
#pragma unroll
            for (int kk = 0; kk < 2; ++kk)
                sf = __builtin_amdgcn_mfma_f32_16x16x32_bf16(
                    kf[cc * 2 + kk], qf[kk], sf, 0, 0, 0);
            const int c0 = s0 + es * 32 + cc * 16;
            if (c0 + 15 > qrow0) {      // diagonal-crossing: mask (s <= q)
                const int rowabs = qrow0 + l15;          // q
                const int colbase = c0 + quad * 4;       // s of reg 0
#pragma unroll
                for (int r = 0; r < 4; ++r)
                    sf[r] = (colbase + r <= rowabs) ? sf[r] : -__builtin_inff();
            }
            u32 pk[2];
            pk[0] = pkbf(exp2f(sf[0]), exp2f(sf[1]));
            pk[1] = pkbf(exp2f(sf[2]), exp2f(sf[3]));
            *(uint2*)&Plds[jt & 1][(qs * 16 + l15) * 72 + es * 32 + cc * 16 + quad * 4]
                = *(const uint2*)pk;
        }
    };

    // ---- prologue: tile 0 ----
    stageV(0, 0);
    {
        bf16x8 kf0[4];
        loadK(0, kf0);
        computeP(0, kf0);
    }

    for (int it = 0; it < ntiles; ++it) {
        __syncthreads();                 // V(it), P(it) ready (vmcnt drained)
        const int buf = it & 1;
        const bool haveNext = (it + 1 < ntiles);
        const bool nextActive = haveNext && ((it + 1) * 64 <= qlim);
        const bool curActive = (it * 64 <= qlim);

        if (haveNext) stageV(buf ^ 1, it + 1);
        bf16x8 kf[4];
        if (nextActive) loadK(it + 1, kf);

        if (curActive) {
            // ---- O += P @ V ; l += P @ 1 ---- (two s-halves h)
#pragma unroll
            for (int h = 0; h < 2; ++h) {
                const bf16x8 pf = *(const bf16x8*)
                    &Plds[buf][(qs * 16 + l15) * 72 + h * 32 + quad * 8];
                accl = __builtin_amdgcn_mfma_f32_16x16x32_bf16(pf, ones, accl, 0, 0, 0);
#pragma unroll
                for (int nb = 0; nb < 8; ++nb) {
                    bf16x8 vf = *(const bf16x8*)
                        &Vlds[buf][(h * 16 + es * 8 + nb) * 512 + lane * 8];
                    acc[nb] = __builtin_amdgcn_mfma_f32_16x16x32_bf16(
                        pf, vf, acc[nb], 0, 0, 0);
                }
            }
        }

        if (nextActive) computeP(it + 1, kf);
    }

    // ---- epilogue: normalize by row sums ----
    float rl[4];
#pragma unroll
    for (int r = 0; r < 4; ++r) rl[r] = 1.0f / accl[r];
#pragma unroll
    for (int nb = 0; nb < 8; ++nb)
#pragma unroll
        for (int r = 0; r < 4; ++r) {
            const int row = qrow0 + quad * 4 + r;
            const int col = e0 + es * 128 + nb * 16 + l15;
            Out[(size_t)(bt0 + row) * 1024 + col] = acc[nb][r] * rl[r];
        }
}

// ----------------------------------------------------------------------------
extern "C" void kernel_launch(void* const* d_in, const int* in_sizes, int n_in,
                              void* d_out, int out_size, void* d_ws, size_t ws_size,
                              hipStream_t stream) {
    const float* x  = (const float*)d_in[0];   // [4,4096,1024]
    const float* Wk = (const float*)d_in[1];   // [64,1024]
    const float* Wq = (const float*)d_in[2];   // [64,1024]
    const float* Wv = (const float*)d_in[3];   // [1024,1024]

    const int nx  = in_sizes[0];
    const int nwk = in_sizes[1];
    const int nwq = in_sizes[2];
    const int nwv = in_sizes[3];

    u16* xb  = (u16*)d_ws;
    u16* Wkb = xb  + (size_t)nx;
    u16* Wqb = Wkb + (size_t)nwk;
    u16* Wvb = Wqb + (size_t)nwq;
    u16* Qf  = Wvb + (size_t)nwv;                    // 1024 btiles * 2 * 512
    u16* Kf  = Qf  + (size_t)1024 * 2 * 512;
    u16* Vf  = Kf  + (size_t)1024 * 2 * 512;         // 64 etiles * 512 * 512
    float* out = (float*)d_out;

    const float qscale = 0.125f * 1.44269504088896f; // fold 1/sqrt(H)*log2(e)

    cvt_x<<<nx / 2048, 256, 0, stream>>>(x, xb, nx);
    cvt_w<<<(nwk + nwq + nwv) / 2048, 256, 0, stream>>>(Wk, Wq, Wv,
                                                        Wkb, Wqb, Wvb, qscale);

    gemm_all<<<1152, 256, 0, stream>>>(xb, Wqb, Wkb, Wvb, Qf, Kf, Vf);

    attn_fa<<<dim3(128, 4), 1024, 0, stream>>>(Qf, Kf, Vf, out);
}